// Round 3
// baseline (127.334 us; speedup 1.0000x reference)
//
#include <hip/hip_runtime.h>

// Entire 4-qubit/3-layer circuit + linear head folded into 8 batch-uniform
// rank-4 tensors C[s][c][t0][t1][t2][t3] (t in {1,cos,sin} basis per wire):
//   logit_c(circuit s) = sum_t C * prod_q (1, cos th_q, sin th_q)[t_q]
// Derivation: psi = U phi, U = (H D2)(H D1)(H D0) uniform; phi real product
// state; z_w = phi^T Re(U^H Z_w U) phi; c^2=(1+cos)/2, s^2=(1-cos)/2, cs=sin/2.
//
// ws layout: float4 tab[m][27], m = s*2+c, index r = t0*9+t1*3+t2,
//            components (t3=0,1,2, pad). 216 float4 = 3456 B.

__device__ __forceinline__ float layer_angle(const float* __restrict__ w,
                                             int l, int idx) {
    float ang = 0.f;
    #pragma unroll
    for (int g = 0; g < 4; ++g) {
        int cb = (idx >> (3 - g)) & 1;                 // control = wire g
        int tb = (idx >> (3 - ((g + 1) & 3))) & 1;     // target  = wire (g+1)%4
        if (cb) ang += (tb ? 0.5f : -0.5f) * w[l * 4 + g];
    }
    return ang;
}

__global__ __launch_bounds__(256) void precompute_tensors(
    const float* __restrict__ weights,
    const float* __restrict__ lin_w,
    float* __restrict__ ws)
{
    __shared__ float2 U1[256], U2[256], U[256];   // row-major [i*16+j]
    __shared__ float zeta[8][16];
    __shared__ float G[8][256];
    __shared__ float A[8][3][64];
    __shared__ float B[8][9][16];
    __shared__ float C1[8][27][4];
    int t = threadIdx.x;
    int i = t >> 4, j = t & 15;

    // U1 = Hhat * D0   (Hhat[i][j] = (-1)^popc(i&j), unnormalized)
    {
        float sgn = (__popc(i & j) & 1) ? -1.f : 1.f;
        float a = layer_angle(weights, 0, j);
        U1[t] = make_float2(sgn * __cosf(a), sgn * __sinf(a));
    }
    // zeta[m][k] = sum_w lin_w[c,4s+w] * (-1)^{bit(3-w) of k},  m = s*2+c
    if (t < 128) {
        int m = t >> 4, k = t & 15;
        int s = m >> 1, c = m & 1;
        float z = 0.f;
        #pragma unroll
        for (int w = 0; w < 4; ++w) {
            float sg = ((k >> (3 - w)) & 1) ? -1.f : 1.f;
            z += lin_w[c * 16 + s * 4 + w] * sg;
        }
        zeta[m][k] = z;
    }
    __syncthreads();
    // U2 = Hhat * D1 * U1
    {
        float ar = 0.f, ai = 0.f;
        for (int k = 0; k < 16; ++k) {
            float sgn = (__popc(i & k) & 1) ? -1.f : 1.f;
            float a = layer_angle(weights, 1, k);
            float cr = sgn * __cosf(a), ci = sgn * __sinf(a);
            float2 u = U1[k * 16 + j];
            ar += cr * u.x - ci * u.y;
            ai += cr * u.y + ci * u.x;
        }
        U2[t] = make_float2(ar, ai);
    }
    __syncthreads();
    // U = Hhat * D2 * U2
    {
        float ar = 0.f, ai = 0.f;
        for (int k = 0; k < 16; ++k) {
            float sgn = (__popc(i & k) & 1) ? -1.f : 1.f;
            float a = layer_angle(weights, 2, k);
            float cr = sgn * __cosf(a), ci = sgn * __sinf(a);
            float2 u = U2[k * 16 + j];
            ar += cr * u.x - ci * u.y;
            ai += cr * u.y + ci * u.x;
        }
        U[t] = make_float2(ar, ai);
    }
    __syncthreads();
    // G[m][i*16+j] = sum_k zeta[m][k] * Re(conj(U[k,i]) U[k,j])
    {
        float g[8] = {0, 0, 0, 0, 0, 0, 0, 0};
        for (int k = 0; k < 16; ++k) {
            float2 uki = U[k * 16 + i], ukj = U[k * 16 + j];
            float p = uki.x * ukj.x + uki.y * ukj.y;
            #pragma unroll
            for (int m = 0; m < 8; ++m) g[m] += zeta[m][k] * p;
        }
        #pragma unroll
        for (int m = 0; m < 8; ++m) G[m][t] = g[m];
    }
    __syncthreads();
    // Fold wire3 (LSB): A[m][t3][ih*8+jh], ih,jh in [0,8)
    for (int e = t; e < 1536; e += 256) {
        int m = e / 192, r = e % 192;
        int t3 = r / 64, q = r % 64;
        int ih = q >> 3, jh = q & 7;
        float g00 = G[m][(ih * 2 + 0) * 16 + jh * 2 + 0];
        float g01 = G[m][(ih * 2 + 0) * 16 + jh * 2 + 1];
        float g10 = G[m][(ih * 2 + 1) * 16 + jh * 2 + 0];
        float g11 = G[m][(ih * 2 + 1) * 16 + jh * 2 + 1];
        A[m][t3][q] = (t3 == 0) ? g00 + g11 : (t3 == 1) ? g00 - g11 : g01 + g10;
    }
    __syncthreads();
    // Fold wire2: B[m][t2*3+t3][ih*4+jh], ih,jh in [0,4)
    for (int e = t; e < 1152; e += 256) {
        int m = e / 144, r = e % 144;
        int t2 = r / 48; r %= 48;
        int t3 = r / 16, q = r % 16;
        int ih = q >> 2, jh = q & 3;
        float a00 = A[m][t3][(ih * 2 + 0) * 8 + jh * 2 + 0];
        float a01 = A[m][t3][(ih * 2 + 0) * 8 + jh * 2 + 1];
        float a10 = A[m][t3][(ih * 2 + 1) * 8 + jh * 2 + 0];
        float a11 = A[m][t3][(ih * 2 + 1) * 8 + jh * 2 + 1];
        B[m][t2 * 3 + t3][q] = (t2 == 0) ? a00 + a11
                             : (t2 == 1) ? a00 - a11 : a01 + a10;
    }
    __syncthreads();
    // Fold wire1: C1[m][t1*9+t2*3+t3][ih*2+jh], ih,jh in {0,1}
    for (int e = t; e < 864; e += 256) {
        int m = e / 108, r = e % 108;
        int t1 = r / 36; r %= 36;
        int t23 = r / 4, q = r % 4;
        int ih = q >> 1, jh = q & 1;
        float b00 = B[m][t23][(ih * 2 + 0) * 4 + jh * 2 + 0];
        float b01 = B[m][t23][(ih * 2 + 0) * 4 + jh * 2 + 1];
        float b10 = B[m][t23][(ih * 2 + 1) * 4 + jh * 2 + 0];
        float b11 = B[m][t23][(ih * 2 + 1) * 4 + jh * 2 + 1];
        C1[m][t1 * 9 + t23][q] = (t1 == 0) ? b00 + b11
                               : (t1 == 1) ? b00 - b11 : b01 + b10;
    }
    __syncthreads();
    // Fold wire0 + write out. Scale: (1/64)^2 for H norm, (1/2)^4 for P.
    const float scale = 1.f / 65536.f;
    float4* ws4 = (float4*)ws;
    for (int e = t; e < 216; e += 256) {
        int m = e / 27, r = e % 27;
        int t0 = r / 9, t12 = r % 9;
        float v[3];
        #pragma unroll
        for (int t3 = 0; t3 < 3; ++t3) {
            const float* c = C1[m][(t12 / 3) * 9 + (t12 % 3) * 3 + t3];
            v[t3] = ((t0 == 0) ? c[0] + c[3] : (t0 == 1) ? c[0] - c[3]
                                             : c[1] + c[2]) * scale;
        }
        ws4[m * 27 + r] = make_float4(v[0], v[1], v[2], 0.f);
    }
}

__global__ __launch_bounds__(256) void qcircuit_kernel(
    const float* __restrict__ x,
    const float* __restrict__ lin_b,
    const float4* __restrict__ tab,
    float* __restrict__ out,
    int nthreads)
{
    int t = blockIdx.x * blockDim.x + threadIdx.x;
    if (t >= nthreads) return;
    int b = t >> 2;
    int s = t & 3;

    const float* xr = x + (size_t)b * 16;
    int base = ((s >> 1) << 3) + ((s & 1) << 1);
    float2 q0 = *(const float2*)(xr + base);       // theta wire0, wire1
    float2 q1 = *(const float2*)(xr + base + 4);   // theta wire2, wire3

    float C0, S0, Cw1, Sw1, C2, S2, C3, S3;
    __sincosf(q0.x, &S0, &C0);
    __sincosf(q0.y, &Sw1, &Cw1);
    __sincosf(q1.x, &S2, &C2);
    __sincosf(q1.y, &S3, &C3);

    float W[3] = {1.f, C0, S0};     // wire0 -> t0
    float X[3] = {1.f, Cw1, Sw1};   // wire1 -> t1

    float lg[2];
    #pragma unroll
    for (int c = 0; c < 2; ++c) {
        const float4* T = tab + (s * 2 + c) * 27;
        float l = 0.f;
        #pragma unroll
        for (int t0 = 0; t0 < 3; ++t0) {
            float a0 = 0.f;
            #pragma unroll
            for (int t1 = 0; t1 < 3; ++t1) {
                float4 v0 = T[t0 * 9 + t1 * 3 + 0];
                float4 v1 = T[t0 * 9 + t1 * 3 + 1];
                float4 v2 = T[t0 * 9 + t1 * 3 + 2];
                float u0 = v0.x + C3 * v0.y + S3 * v0.z;   // wire3 -> t3
                float u1 = v1.x + C3 * v1.y + S3 * v1.z;
                float u2 = v2.x + C3 * v2.y + S3 * v2.z;
                float a1 = u0 + C2 * u1 + S2 * u2;         // wire2 -> t2
                a0 += X[t1] * a1;
            }
            l += W[t0] * a0;
        }
        lg[c] = l;
    }

    // reduce across the 4 circuits of this batch row
    float l0 = lg[0], l1 = lg[1];
    l0 += __shfl_xor(l0, 1); l0 += __shfl_xor(l0, 2);
    l1 += __shfl_xor(l1, 1); l1 += __shfl_xor(l1, 2);

    if (s == 0) {
        l0 += lin_b[0];
        l1 += lin_b[1];
        float m = fmaxf(l0, l1);
        float e0 = __expf(l0 - m), e1 = __expf(l1 - m);
        float inv = 1.f / (e0 + e1);
        *(float2*)(out + (size_t)b * 2) = make_float2(e0 * inv, e1 * inv);
    }
}

extern "C" void kernel_launch(void* const* d_in, const int* in_sizes, int n_in,
                              void* d_out, int out_size, void* d_ws, size_t ws_size,
                              hipStream_t stream) {
    const float* x       = (const float*)d_in[0];
    const float* weights = (const float*)d_in[1];
    const float* lin_w   = (const float*)d_in[2];
    const float* lin_b   = (const float*)d_in[3];
    float* out = (float*)d_out;
    float* ws  = (float*)d_ws;

    int bsz = in_sizes[0] / 16;
    int nthreads = bsz * 4;

    precompute_tensors<<<1, 256, 0, stream>>>(weights, lin_w, ws);

    int block = 256;
    int grid = (nthreads + block - 1) / block;
    qcircuit_kernel<<<grid, block, 0, stream>>>(x, lin_b, (const float4*)ws,
                                                out, nthreads);
}

// Round 4
// 77.525 us; speedup vs baseline: 1.6425x; 1.6425x over previous
//
#include <hip/hip_runtime.h>

// Circuit + linear head + softmax folded into 4 batch-uniform DIFFERENCE
// tensors Td[s][t0][t1][t2][t3] (t in {1,cos,sin} basis per wire):
//   l0 - l1 = sum_s sum_t Td[s] * prod_q (1,cos th_q,sin th_q)[t_q]
//   softmax = sigmoid(l0-l1) for 2 classes.
// One thread per batch row: all table indices are wave-uniform constants ->
// s_load/SGPR path (R3's per-lane VMEM table reads were the 60us stall).
//
// ws layout: float tab[s][81], index t0*27+t1*9+t2*3+t3.  324 floats.

__device__ __forceinline__ float layer_angle(const float* __restrict__ w,
                                             int l, int idx) {
    float ang = 0.f;
    #pragma unroll
    for (int g = 0; g < 4; ++g) {
        int cb = (idx >> (3 - g)) & 1;                 // control = wire g
        int tb = (idx >> (3 - ((g + 1) & 3))) & 1;     // target  = wire (g+1)%4
        if (cb) ang += (tb ? 0.5f : -0.5f) * w[l * 4 + g];
    }
    return ang;
}

__global__ __launch_bounds__(256) void precompute_tensors(
    const float* __restrict__ weights,
    const float* __restrict__ lin_w,
    float* __restrict__ ws)
{
    __shared__ float2 U1[256], U2[256], U[256];   // row-major [i*16+j]
    __shared__ float zeta[4][16];
    __shared__ float G[4][256];
    __shared__ float A[4][3][64];
    __shared__ float B[4][9][16];
    __shared__ float C1[4][27][4];
    int t = threadIdx.x;
    int i = t >> 4, j = t & 15;

    // U1 = Hhat * D0   (Hhat[i][j] = (-1)^popc(i&j), unnormalized)
    {
        float sgn = (__popc(i & j) & 1) ? -1.f : 1.f;
        float a = layer_angle(weights, 0, j);
        U1[t] = make_float2(sgn * __cosf(a), sgn * __sinf(a));
    }
    // zeta[s][k] = sum_w (lin_w[0,4s+w]-lin_w[1,4s+w]) * (-1)^{bit(3-w) of k}
    if (t < 64) {
        int s = t >> 4, k = t & 15;
        float z = 0.f;
        #pragma unroll
        for (int w = 0; w < 4; ++w) {
            float sg = ((k >> (3 - w)) & 1) ? -1.f : 1.f;
            z += (lin_w[s * 4 + w] - lin_w[16 + s * 4 + w]) * sg;
        }
        zeta[s][k] = z;
    }
    __syncthreads();
    // U2 = Hhat * D1 * U1
    {
        float ar = 0.f, ai = 0.f;
        for (int k = 0; k < 16; ++k) {
            float sgn = (__popc(i & k) & 1) ? -1.f : 1.f;
            float a = layer_angle(weights, 1, k);
            float cr = sgn * __cosf(a), ci = sgn * __sinf(a);
            float2 u = U1[k * 16 + j];
            ar += cr * u.x - ci * u.y;
            ai += cr * u.y + ci * u.x;
        }
        U2[t] = make_float2(ar, ai);
    }
    __syncthreads();
    // U = Hhat * D2 * U2
    {
        float ar = 0.f, ai = 0.f;
        for (int k = 0; k < 16; ++k) {
            float sgn = (__popc(i & k) & 1) ? -1.f : 1.f;
            float a = layer_angle(weights, 2, k);
            float cr = sgn * __cosf(a), ci = sgn * __sinf(a);
            float2 u = U2[k * 16 + j];
            ar += cr * u.x - ci * u.y;
            ai += cr * u.y + ci * u.x;
        }
        U[t] = make_float2(ar, ai);
    }
    __syncthreads();
    // G[s][i*16+j] = sum_k zeta[s][k] * Re(conj(U[k,i]) U[k,j])
    {
        float g[4] = {0, 0, 0, 0};
        for (int k = 0; k < 16; ++k) {
            float2 uki = U[k * 16 + i], ukj = U[k * 16 + j];
            float p = uki.x * ukj.x + uki.y * ukj.y;
            #pragma unroll
            for (int s = 0; s < 4; ++s) g[s] += zeta[s][k] * p;
        }
        #pragma unroll
        for (int s = 0; s < 4; ++s) G[s][t] = g[s];
    }
    __syncthreads();
    // Fold wire3 (LSB): A[s][t3][ih*8+jh]
    for (int e = t; e < 768; e += 256) {
        int m = e / 192, r = e % 192;
        int t3 = r / 64, q = r % 64;
        int ih = q >> 3, jh = q & 7;
        float g00 = G[m][(ih * 2 + 0) * 16 + jh * 2 + 0];
        float g01 = G[m][(ih * 2 + 0) * 16 + jh * 2 + 1];
        float g10 = G[m][(ih * 2 + 1) * 16 + jh * 2 + 0];
        float g11 = G[m][(ih * 2 + 1) * 16 + jh * 2 + 1];
        A[m][t3][q] = (t3 == 0) ? g00 + g11 : (t3 == 1) ? g00 - g11 : g01 + g10;
    }
    __syncthreads();
    // Fold wire2: B[s][t2*3+t3][ih*4+jh]
    for (int e = t; e < 576; e += 256) {
        int m = e / 144, r = e % 144;
        int t2 = r / 48; r %= 48;
        int t3 = r / 16, q = r % 16;
        int ih = q >> 2, jh = q & 3;
        float a00 = A[m][t3][(ih * 2 + 0) * 8 + jh * 2 + 0];
        float a01 = A[m][t3][(ih * 2 + 0) * 8 + jh * 2 + 1];
        float a10 = A[m][t3][(ih * 2 + 1) * 8 + jh * 2 + 0];
        float a11 = A[m][t3][(ih * 2 + 1) * 8 + jh * 2 + 1];
        B[m][t2 * 3 + t3][q] = (t2 == 0) ? a00 + a11
                             : (t2 == 1) ? a00 - a11 : a01 + a10;
    }
    __syncthreads();
    // Fold wire1: C1[s][t1*9+t2*3+t3][ih*2+jh]
    for (int e = t; e < 432; e += 256) {
        int m = e / 108, r = e % 108;
        int t1 = r / 36; r %= 36;
        int t23 = r / 4, q = r % 4;
        int ih = q >> 1, jh = q & 1;
        float b00 = B[m][t23][(ih * 2 + 0) * 4 + jh * 2 + 0];
        float b01 = B[m][t23][(ih * 2 + 0) * 4 + jh * 2 + 1];
        float b10 = B[m][t23][(ih * 2 + 1) * 4 + jh * 2 + 0];
        float b11 = B[m][t23][(ih * 2 + 1) * 4 + jh * 2 + 1];
        C1[m][t1 * 9 + t23][q] = (t1 == 0) ? b00 + b11
                               : (t1 == 1) ? b00 - b11 : b01 + b10;
    }
    __syncthreads();
    // Fold wire0 + write. Scale: (1/64)^2 H-norm, (1/2)^4 half-angle basis.
    const float scale = 1.f / 65536.f;
    for (int e = t; e < 324; e += 256) {
        int m = e / 81, r = e % 81;
        int t0 = r / 27, t123 = r % 27;
        const float* c = C1[m][t123];
        float v = (t0 == 0) ? c[0] + c[3] : (t0 == 1) ? c[0] - c[3]
                                          : c[1] + c[2];
        ws[m * 81 + r] = v * scale;
    }
}

__global__ __launch_bounds__(256) void qcircuit_kernel(
    const float* __restrict__ x,
    const float* __restrict__ lin_b,
    const float* __restrict__ tab,   // uniform -> scalar loads
    float* __restrict__ out,
    int nrows)
{
    int b = blockIdx.x * blockDim.x + threadIdx.x;
    if (b >= nrows) return;

    const float* xr = x + (size_t)b * 16;
    float4 xa = *(const float4*)(xr);
    float4 xb = *(const float4*)(xr + 4);
    float4 xc = *(const float4*)(xr + 8);
    float4 xd = *(const float4*)(xr + 12);
    float xs[16] = {xa.x, xa.y, xa.z, xa.w, xb.x, xb.y, xb.z, xb.w,
                    xc.x, xc.y, xc.z, xc.w, xd.x, xd.y, xd.z, xd.w};
    float cs[16], sn[16];
    #pragma unroll
    for (int i = 0; i < 16; ++i) __sincosf(xs[i], &sn[i], &cs[i]);

    float d = 0.f;
    #pragma unroll
    for (int s = 0; s < 4; ++s) {
        int b0 = ((s >> 1) << 3) + ((s & 1) << 1);
        // wires 0,1,2,3 of circuit s -> x indices b0, b0+1, b0+4, b0+5
        float W[3] = {1.f, cs[b0],     sn[b0]};       // t0
        float X[3] = {1.f, cs[b0 + 1], sn[b0 + 1]};   // t1
        float C2 = cs[b0 + 4], S2 = sn[b0 + 4];       // t2
        float C3 = cs[b0 + 5], S3 = sn[b0 + 5];       // t3
        const float* T = tab + s * 81;
        #pragma unroll
        for (int t0 = 0; t0 < 3; ++t0) {
            float a0 = 0.f;
            #pragma unroll
            for (int t1 = 0; t1 < 3; ++t1) {
                const float* T3 = T + t0 * 27 + t1 * 9;
                float u0 = T3[0] + C3 * T3[1] + S3 * T3[2];
                float u1 = T3[3] + C3 * T3[4] + S3 * T3[5];
                float u2 = T3[6] + C3 * T3[7] + S3 * T3[8];
                float a1 = u0 + C2 * u1 + S2 * u2;
                a0 += X[t1] * a1;
            }
            d += W[t0] * a0;
        }
    }

    d += lin_b[0] - lin_b[1];
    // softmax over 2 logits == sigmoid of the difference
    float p0 = 1.f / (1.f + __expf(-d));
    *(float2*)(out + (size_t)b * 2) = make_float2(p0, 1.f - p0);
}

extern "C" void kernel_launch(void* const* d_in, const int* in_sizes, int n_in,
                              void* d_out, int out_size, void* d_ws, size_t ws_size,
                              hipStream_t stream) {
    const float* x       = (const float*)d_in[0];
    const float* weights = (const float*)d_in[1];
    const float* lin_w   = (const float*)d_in[2];
    const float* lin_b   = (const float*)d_in[3];
    float* out = (float*)d_out;
    float* ws  = (float*)d_ws;

    int nrows = in_sizes[0] / 16;

    precompute_tensors<<<1, 256, 0, stream>>>(weights, lin_w, ws);

    int block = 256;
    int grid = (nrows + block - 1) / block;
    qcircuit_kernel<<<grid, block, 0, stream>>>(x, lin_b, ws, out, nrows);
}